// Round 9
// baseline (299.547 us; speedup 1.0000x reference)
//
#include <hip/hip_runtime.h>

#define NEG_SLOPE 0.2f
#define LN_EPS 1e-5f

typedef __attribute__((ext_vector_type(8))) short bf16x8;
typedef __attribute__((ext_vector_type(4))) float f32x4;

__device__ inline unsigned short f2bf(float f) {
    unsigned u = __float_as_uint(f);
    unsigned r = u + 0x7FFFu + ((u >> 16) & 1u);   // round-to-nearest-even
    return (unsigned short)(r >> 16);
}

__device__ inline void unpack8(uint4 u, float* f) {
    f[0] = __uint_as_float(u.x << 16);
    f[1] = __uint_as_float(u.x & 0xFFFF0000u);
    f[2] = __uint_as_float(u.y << 16);
    f[3] = __uint_as_float(u.y & 0xFFFF0000u);
    f[4] = __uint_as_float(u.z << 16);
    f[5] = __uint_as_float(u.z & 0xFFFF0000u);
    f[6] = __uint_as_float(u.w << 16);
    f[7] = __uint_as_float(u.w & 0xFFFF0000u);
}

// ---------------- k0: zero counts+dhist+dcount + W transpose (fused) ------------

__global__ __launch_bounds__(256) void zero_wt_kernel(
    uint4* __restrict__ z, int nz, int ZB,
    const float* __restrict__ W0, const float* __restrict__ W1,
    const float* __restrict__ W2, unsigned short* __restrict__ Wt0,
    unsigned short* __restrict__ Wt1, unsigned short* __restrict__ Wt2) {
    int bid = blockIdx.x;
    if (bid < ZB) {
        int base = bid * 1024 + threadIdx.x;
        #pragma unroll
        for (int j = 0; j < 4; ++j) {
            int idx = base + j * 256;
            if (idx < nz) z[idx] = make_uint4(0, 0, 0, 0);
        }
    } else {
        int row = (bid - ZB) * 2 + (threadIdx.x >> 7);   // 0..319
        int k = threadIdx.x & 127;
        if (row < 128) {
            Wt0[row * 128 + k] = f2bf(W0[k * 128 + row]);
        } else if (row < 256) {
            int c = row - 128;
            Wt1[c * 128 + k] = f2bf(W1[k * 128 + c]);
        } else {
            int c = row - 256;
            Wt2[c * 128 + k] = f2bf(W2[k * 64 + c]);
        }
    }
}

// ---------------- k1: degree histogram (rank) + layer-0 GEMM, fused ----------------

__global__ __launch_bounds__(256) void hist_gemm0(
    const int* __restrict__ dst, int* __restrict__ counts, int* __restrict__ rank,
    int E, int RB, const float* __restrict__ Ap, const unsigned short* __restrict__ Wt,
    const float* __restrict__ al, const float* __restrict__ ar,
    unsigned short* __restrict__ ftb, float* __restrict__ el,
    float* __restrict__ er, int n) {
    constexpr int LDA = 136;  // bf16 elems per LDS row (128 + 8 pad)
    constexpr int NT = 8, H = 4, D = 32;
    __shared__ unsigned short As[64 * LDA];
    __shared__ unsigned short Ws[NT * 16 * LDA];
    int t = threadIdx.x;
    if (blockIdx.x < RB) {
        int i = blockIdx.x * 256 + t;
        if (i < E) rank[i] = atomicAdd(&counts[dst[i] * 16], 1);
        return;
    }
    int row0 = (blockIdx.x - RB) * 64;

    const float4* A4 = (const float4*)Ap;
    #pragma unroll
    for (int j = 0; j < 8; ++j) {
        int idx = t + j * 256;  // float4 index within 64x128 tile
        int r = idx >> 5;
        int c4 = idx & 31;
        int row = row0 + r;
        float4 v = (row < n) ? A4[(size_t)row * 32 + c4] : make_float4(0.f, 0.f, 0.f, 0.f);
        unsigned p0 = (unsigned)f2bf(v.x) | ((unsigned)f2bf(v.y) << 16);
        unsigned p1 = (unsigned)f2bf(v.z) | ((unsigned)f2bf(v.w) << 16);
        *(uint2*)&As[r * LDA + c4 * 4] = make_uint2(p0, p1);
    }
    const uint4* Wg = (const uint4*)Wt;
    #pragma unroll
    for (int j = 0; j < NT; ++j) {
        int idx = t + j * 256;
        int r = idx >> 4;
        int c8 = idx & 15;
        *(uint4*)&Ws[r * LDA + c8 * 8] = Wg[idx];
    }
    __syncthreads();

    int w = t >> 6, lane = t & 63;
    int m = lane & 15, q = lane >> 4;
    f32x4 acc[NT] = {};
    const unsigned short* ap = &As[(w * 16 + m) * LDA + q * 8];
    #pragma unroll
    for (int kk = 0; kk < 4; ++kk) {
        bf16x8 a = *(const bf16x8*)(ap + kk * 32);
        #pragma unroll
        for (int nt = 0; nt < NT; ++nt) {
            bf16x8 b = *(const bf16x8*)&Ws[(nt * 16 + m) * LDA + kk * 32 + q * 8];
            acc[nt] = __builtin_amdgcn_mfma_f32_16x16x32_bf16(a, b, acc[nt], 0, 0, 0);
        }
    }

    float alv[NT], arv[NT];
    #pragma unroll
    for (int nt = 0; nt < NT; ++nt) {
        alv[nt] = al[nt * 16 + m];
        arv[nt] = ar[nt * 16 + m];
    }

    int orow = row0 + w * 16 + q * 4;
    #pragma unroll
    for (int r = 0; r < 4; ++r) {
        int row = orow + r;
        float pl[H] = {}, pr[H] = {};
        #pragma unroll
        for (int nt = 0; nt < NT; ++nt) {
            int h = (nt * 16) / D;
            pl[h] = fmaf(acc[nt][r], alv[nt], pl[h]);
            pr[h] = fmaf(acc[nt][r], arv[nt], pr[h]);
        }
        #pragma unroll
        for (int off = 1; off < 16; off <<= 1) {
            #pragma unroll
            for (int h = 0; h < H; ++h) {
                pl[h] += __shfl_xor(pl[h], off, 64);
                pr[h] += __shfl_xor(pr[h], off, 64);
            }
        }
        if (row < n) {
            #pragma unroll
            for (int nt = 0; nt < NT; ++nt)
                ftb[(size_t)row * 128 + nt * 16 + m] = f2bf(acc[nt][r]);
            if (m < H) {
                float vl = pl[0], vr = pr[0];
                #pragma unroll
                for (int h = 1; h < H; ++h)
                    if (m == h) { vl = pl[h]; vr = pr[h]; }
                el[row * H + m] = vl;
                er[row * H + m] = vr;
            }
        }
    }
}

// ---------------- k2: scan1 — block sums + 64-bin degree histogram ----------------
// key = 63 - min(deg,63): descending-degree counting sort for the agg perm.

__global__ __launch_bounds__(256) void scan1_kernel(const int* __restrict__ counts,
                                                    int* __restrict__ bsum,
                                                    int* __restrict__ dhist, int n) {
    __shared__ int lds[256];
    __shared__ int hbin[64];
    int t = threadIdx.x;
    if (t < 64) hbin[t] = 0;
    int i = blockIdx.x * 256 + t;
    int c = (i < n) ? counts[i * 16] : 0;
    lds[t] = c;
    __syncthreads();
    if (i < n) atomicAdd(&hbin[63 - (c < 63 ? c : 63)], 1);
    for (int off = 128; off > 0; off >>= 1) {
        int v = (t < off) ? lds[t + off] : 0;
        __syncthreads();
        if (t < off) lds[t] += v;
        __syncthreads();
    }
    if (t == 0) bsum[blockIdx.x] = lds[0];
    if (t < 64) {
        int h = hbin[t];
        if (h) atomicAdd(&dhist[t], h);
    }
}

// ---------------- k3: fused scan2+scan3 -> rowptr; block0 scans dhist -> dbase ----

__global__ __launch_bounds__(256) void scan3_kernel(const int* __restrict__ counts,
                                                    const int* __restrict__ bsum,
                                                    int* __restrict__ rowptr,
                                                    const int* __restrict__ dhist,
                                                    int* __restrict__ dbase,
                                                    int n, int E, int nscan) {
    __shared__ int lds[256];
    int t = threadIdx.x;
    // pass A: inclusive scan of bsum
    lds[t] = (t < nscan) ? bsum[t] : 0;
    __syncthreads();
    for (int off = 1; off < 256; off <<= 1) {
        int v = (t >= off) ? lds[t - off] : 0;
        __syncthreads();
        lds[t] += v;
        __syncthreads();
    }
    int boff = (blockIdx.x > 0) ? lds[blockIdx.x - 1] : 0;
    __syncthreads();
    // pass B: scan this block's counts
    int i = blockIdx.x * 256 + t;
    int c = (i < n) ? counts[i * 16] : 0;
    lds[t] = c;
    __syncthreads();
    for (int off = 1; off < 256; off <<= 1) {
        int v = (t >= off) ? lds[t - off] : 0;
        __syncthreads();
        lds[t] += v;
        __syncthreads();
    }
    if (i < n) rowptr[i] = boff + lds[t] - c;  // exclusive prefix
    if (i == n) rowptr[n] = E;
    // bin scan (one wave)
    if (blockIdx.x == 0 && t < 64) {
        int v = dhist[t];
        int x = v;
        #pragma unroll
        for (int off = 1; off < 64; off <<= 1) {
            int u = __shfl_up(x, off, 64);
            if (t >= off) x += u;
        }
        dbase[t] = x - v;
    }
}

// ---------------- k4: placement + perm scatter ----------------

__global__ __launch_bounds__(256) void place_kernel(
    const int* __restrict__ src, const int* __restrict__ dst,
    const float* __restrict__ ew, const int* __restrict__ rowptr,
    const int* __restrict__ rank, unsigned* __restrict__ edge_p,
    const int* __restrict__ dbase, int* __restrict__ dcount,
    int* __restrict__ perm, int E, int EB, int N) {
    __shared__ int lbin[64];
    __shared__ int lbase[64];
    int bid = blockIdx.x;
    int t = threadIdx.x;
    if (bid < EB) {
        int i = bid * 256 + t;
        if (i < E) {
            int p = rowptr[dst[i]] + rank[i];
            edge_p[p] = ((unsigned)f2bf(ew[i]) << 16) | (unsigned)src[i];
        }
    } else {
        if (t < 64) lbin[t] = 0;
        __syncthreads();
        int nidx = (bid - EB) * 256 + t;
        bool valid = nidx < N;
        int key = 0, myoff = 0;
        if (valid) {
            int deg = rowptr[nidx + 1] - rowptr[nidx];
            key = 63 - (deg < 63 ? deg : 63);
            myoff = atomicAdd(&lbin[key], 1);
        }
        __syncthreads();
        if (t < 64) lbase[t] = lbin[t] ? atomicAdd(&dcount[t], lbin[t]) : 0;
        __syncthreads();
        if (valid) perm[dbase[key] + lbase[key] + myoff] = nidx;
    }
}

// ---------------- agg helpers ----------------

__device__ inline void accum8(float* ax, uint4 u, float p) {
    ax[0] = fmaf(p, __uint_as_float(u.x << 16), ax[0]);
    ax[1] = fmaf(p, __uint_as_float(u.x & 0xFFFF0000u), ax[1]);
    ax[2] = fmaf(p, __uint_as_float(u.y << 16), ax[2]);
    ax[3] = fmaf(p, __uint_as_float(u.y & 0xFFFF0000u), ax[3]);
    ax[4] = fmaf(p, __uint_as_float(u.z << 16), ax[4]);
    ax[5] = fmaf(p, __uint_as_float(u.z & 0xFFFF0000u), ax[5]);
    ax[6] = fmaf(p, __uint_as_float(u.w << 16), ax[6]);
    ax[7] = fmaf(p, __uint_as_float(u.w & 0xFFFF0000u), ax[7]);
}

__device__ inline void accum4(float* ax, uint2 u, float p) {
    ax[0] = fmaf(p, __uint_as_float(u.x << 16), ax[0]);
    ax[1] = fmaf(p, __uint_as_float(u.x & 0xFFFF0000u), ax[1]);
    ax[2] = fmaf(p, __uint_as_float(u.y << 16), ax[2]);
    ax[3] = fmaf(p, __uint_as_float(u.y & 0xFFFF0000u), ax[3]);
}

// K edges: issue ALL K ftb gathers + K el loads before any consume (MLP depth K).
// Accumulation order is k-ascending — identical numerics at any K.
template <int K>
__device__ inline void agg_batch(const uint4* __restrict__ ftb4,
                                 const float* __restrict__ el, unsigned ev, int j,
                                 int li, int head, float erv, float lam, float* ax,
                                 float& s) {
    unsigned ee[K];
    uint4 uu[K];
    float ll[K];
    #pragma unroll
    for (int k = 0; k < K; ++k) ee[k] = __shfl(ev, j + k, 16);
    #pragma unroll
    for (int k = 0; k < K; ++k) {
        unsigned sn = ee[k] & 0xFFFFu;
        uu[k] = ftb4[(size_t)sn * 16 + li];
        ll[k] = el[sn * 4 + head];
    }
    #pragma unroll
    for (int k = 0; k < K; ++k) {
        float v = ll[k] + erv + lam * __uint_as_float(ee[k] & 0xFFFF0000u);
        v = fmaxf(v, NEG_SLOPE * v);
        float p = __expf(v);
        accum8(ax, uu[k], p);
        s += p;
    }
}

template <int K>
__device__ inline void agg_batch_out(const uint2* __restrict__ ftb2,
                                     const float* __restrict__ el, unsigned ev,
                                     int j, int li, float erv, float lam, float* ax,
                                     float& s) {
    unsigned ee[K];
    uint2 uu[K];
    float ll[K];
    #pragma unroll
    for (int k = 0; k < K; ++k) ee[k] = __shfl(ev, j + k, 16);
    #pragma unroll
    for (int k = 0; k < K; ++k) {
        unsigned sn = ee[k] & 0xFFFFu;
        uu[k] = ftb2[(size_t)sn * 16 + li];
        ll[k] = el[sn];
    }
    #pragma unroll
    for (int k = 0; k < K; ++k) {
        float v = ll[k] + erv + lam * __uint_as_float(ee[k] & 0xFFFF0000u);
        v = fmaxf(v, NEG_SLOPE * v);
        float p = __expf(v);
        accum4(ax, uu[k], p);
        s += p;
    }
}

// ---------------- k5/k6: fused agg+ELU+LN+residual THEN next-layer GEMM ----------
// R8-proven numerics. Gather pipeline deepened to 16 outstanding loads per
// 16-lane group (latency-bound per R8 counters: VALU 33%, HBM 27%, nothing
// saturated; depth was the only free variable).

template <bool PREV32, int VER>
__global__ __launch_bounds__(256) void fused_agg_gemm(
    const int* __restrict__ rowptr, const unsigned* __restrict__ edge_p,
    const int* __restrict__ perm, const uint4* __restrict__ ftb4,
    const float* __restrict__ el_in, const float* __restrict__ er_in,
    const float* __restrict__ lam_p, const float* __restrict__ g,
    const float* __restrict__ b, const void* __restrict__ prevp,
    uint4* __restrict__ houtb, const unsigned short* __restrict__ Wt,
    const float* __restrict__ al, const float* __restrict__ ar,
    unsigned short* __restrict__ ftb_out, float* __restrict__ el_out,
    float* __restrict__ er_out, int n) {
    constexpr int LDA = 136;
    __shared__ unsigned short As[16 * LDA];
    __shared__ float red[2][4][16];
    int t = threadIdx.x;
    int node0 = blockIdx.x * 16;
    int nl = t >> 4;
    int gid = node0 + nl;
    int li = t & 15;

    if (gid < n) {
        int node = perm[gid];
        int head = li >> 2;
        float lam = lam_p[0];
        float erv = er_in[node * 4 + head];
        int s0 = rowptr[node], s1 = rowptr[node + 1];
        float ax[8] = {};
        float s = 0.f;

        for (int base = s0; base < s1; base += 16) {
            int m = s1 - base;
            if (m > 16) m = 16;
            unsigned ev = (li < m) ? edge_p[base + li] : 0u;
            int j = 0;
            for (; j + 16 <= m; j += 16)
                agg_batch<16>(ftb4, el_in, ev, j, li, head, erv, lam, ax, s);
            for (; j + 8 <= m; j += 8)
                agg_batch<8>(ftb4, el_in, ev, j, li, head, erv, lam, ax, s);
            if (j + 4 <= m) {
                agg_batch<4>(ftb4, el_in, ev, j, li, head, erv, lam, ax, s);
                j += 4;
            }
            for (; j < m; ++j)
                agg_batch<1>(ftb4, el_in, ev, j, li, head, erv, lam, ax, s);
        }

        float inv = (s > 0.f) ? 1.f / s : 0.f;
        float x[8];
        float sum = 0.f, sq = 0.f;
        #pragma unroll
        for (int d = 0; d < 8; ++d) {
            float v = ax[d] * inv;
            v = (v > 0.f) ? v : expm1f(v);
            x[d] = v;
            sum += v;
            sq += v * v;
        }
        #pragma unroll
        for (int off = 1; off < 16; off <<= 1) {
            sum += __shfl_xor(sum, off, 16);
            sq += __shfl_xor(sq, off, 16);
        }
        float mu = sum * (1.f / 128.f);
        float var = sq * (1.f / 128.f) - mu * mu;
        float rs = rsqrtf(var + LN_EPS);

        const float4* g4 = (const float4*)g;
        const float4* b4 = (const float4*)b;
        float pv[8];
        if constexpr (PREV32) {
            const float4* p4 = (const float4*)prevp;
            #pragma unroll
            for (int h = 0; h < 2; ++h) {
                float4 v = p4[(size_t)node * 32 + li * 2 + h];
                pv[h * 4 + 0] = v.x; pv[h * 4 + 1] = v.y;
                pv[h * 4 + 2] = v.z; pv[h * 4 + 3] = v.w;
            }
        } else {
            unpack8(((const uint4*)prevp)[(size_t)node * 16 + li], pv);
        }
        float y[8];
        #pragma unroll
        for (int h = 0; h < 2; ++h) {
            float4 gv = g4[li * 2 + h];
            float4 bv = b4[li * 2 + h];
            y[h * 4 + 0] = (x[h * 4 + 0] - mu) * rs * gv.x + bv.x + pv[h * 4 + 0];
            y[h * 4 + 1] = (x[h * 4 + 1] - mu) * rs * gv.y + bv.y + pv[h * 4 + 1];
            y[h * 4 + 2] = (x[h * 4 + 2] - mu) * rs * gv.z + bv.z + pv[h * 4 + 2];
            y[h * 4 + 3] = (x[h * 4 + 3] - mu) * rs * gv.w + bv.w + pv[h * 4 + 3];
        }
        uint4 o;
        o.x = (unsigned)f2bf(y[0]) | ((unsigned)f2bf(y[1]) << 16);
        o.y = (unsigned)f2bf(y[2]) | ((unsigned)f2bf(y[3]) << 16);
        o.z = (unsigned)f2bf(y[4]) | ((unsigned)f2bf(y[5]) << 16);
        o.w = (unsigned)f2bf(y[6]) | ((unsigned)f2bf(y[7]) << 16);
        if constexpr (VER == 1) houtb[(size_t)node * 16 + li] = o;
        *(uint4*)&As[nl * LDA + li * 8] = o;
    } else {
        *(uint4*)&As[nl * LDA + li * 8] = make_uint4(0, 0, 0, 0);
    }
    __syncthreads();

    // ---- GEMM phase on the 16 fresh rows (LDS row srow -> node perm[node0+srow]) --
    int w = t >> 6, lane = t & 63;
    int m = lane & 15, q = lane >> 4;
    if constexpr (VER == 1) {
        f32x4 acc[2] = {};
        #pragma unroll
        for (int kk = 0; kk < 4; ++kk) {
            bf16x8 a = *(const bf16x8*)&As[m * LDA + kk * 32 + q * 8];
            #pragma unroll
            for (int nt = 0; nt < 2; ++nt) {
                int col = w * 32 + nt * 16 + m;
                bf16x8 bb = *(const bf16x8*)&Wt[(size_t)col * 128 + kk * 32 + q * 8];
                acc[nt] = __builtin_amdgcn_mfma_f32_16x16x32_bf16(a, bb, acc[nt], 0, 0, 0);
            }
        }
        float alv0 = al[w * 32 + m], alv1 = al[w * 32 + 16 + m];
        float arv0 = ar[w * 32 + m], arv1 = ar[w * 32 + 16 + m];
        #pragma unroll
        for (int r = 0; r < 4; ++r) {
            int gr = node0 + q * 4 + r;
            float pl = acc[0][r] * alv0 + acc[1][r] * alv1;
            float pr = acc[0][r] * arv0 + acc[1][r] * arv1;
            #pragma unroll
            for (int off = 1; off < 16; off <<= 1) {
                pl += __shfl_xor(pl, off, 64);
                pr += __shfl_xor(pr, off, 64);
            }
            if (m == 0 && gr < n) {
                int trow = perm[gr];
                el_out[trow * 4 + w] = pl;
                er_out[trow * 4 + w] = pr;
            }
        }
        __syncthreads();   // all fragment reads done; safe to overwrite As
        #pragma unroll
        for (int r = 0; r < 4; ++r) {
            int srow = q * 4 + r;
            As[srow * LDA + w * 32 + m] = f2bf(acc[0][r]);
            As[srow * LDA + w * 32 + 16 + m] = f2bf(acc[1][r]);
        }
        __syncthreads();
        {
            int row = t >> 4, c8 = t & 15;
            int gr = node0 + row;
            if (gr < n)
                ((uint4*)ftb_out)[(size_t)perm[gr] * 16 + c8] =
                    *(const uint4*)&As[row * LDA + c8 * 8];
        }
    } else {
        f32x4 acc = {};
        #pragma unroll
        for (int kk = 0; kk < 4; ++kk) {
            bf16x8 a = *(const bf16x8*)&As[m * LDA + kk * 32 + q * 8];
            int col = w * 16 + m;
            bf16x8 bb = *(const bf16x8*)&Wt[(size_t)col * 128 + kk * 32 + q * 8];
            acc = __builtin_amdgcn_mfma_f32_16x16x32_bf16(a, bb, acc, 0, 0, 0);
        }
        float alv = al[w * 16 + m], arv = ar[w * 16 + m];
        #pragma unroll
        for (int r = 0; r < 4; ++r) {
            int srow = q * 4 + r;
            float pl = acc[r] * alv;
            float pr = acc[r] * arv;
            #pragma unroll
            for (int off = 1; off < 16; off <<= 1) {
                pl += __shfl_xor(pl, off, 64);
                pr += __shfl_xor(pr, off, 64);
            }
            if (m == 0) {
                red[0][w][srow] = pl;
                red[1][w][srow] = pr;
            }
        }
        __syncthreads();   // fragment reads + red writes done
        #pragma unroll
        for (int r = 0; r < 4; ++r) {
            int srow = q * 4 + r;
            As[srow * LDA + w * 16 + m] = f2bf(acc[r]);
        }
        __syncthreads();
        if (t < 128) {
            int row = t >> 3, c8 = t & 7;
            int gr = node0 + row;
            if (gr < n)
                ((uint4*)ftb_out)[(size_t)perm[gr] * 8 + c8] =
                    *(const uint4*)&As[row * LDA + c8 * 8];
        }
        if (t < 16) {
            int gr = node0 + t;
            if (gr < n) {
                int trow = perm[gr];
                el_out[trow] = red[0][0][t] + red[0][1][t] + red[0][2][t] + red[0][3][t];
                er_out[trow] = red[1][0][t] + red[1][1][t] + red[1][2][t] + red[1][3][t];
            }
        }
    }
}

// ---------------- k7: final aggregate (H=1, OUT=64) ----------------

__global__ __launch_bounds__(256) void gat_agg_out(
    const int* __restrict__ rowptr, const unsigned* __restrict__ edge_p,
    const int* __restrict__ perm, const uint2* __restrict__ ftb2,
    const float* __restrict__ el, const float* __restrict__ er,
    const float* __restrict__ lam_p, float* __restrict__ out, int n) {
    int gid = blockIdx.x * 16 + (threadIdx.x >> 4);
    if (gid >= n) return;
    int node = perm[gid];
    int li = threadIdx.x & 15;
    float lam = lam_p[0];
    float erv = er[node];
    int s0 = rowptr[node], s1 = rowptr[node + 1];
    float ax[4] = {};
    float s = 0.f;

    for (int base = s0; base < s1; base += 16) {
        int m = s1 - base;
        if (m > 16) m = 16;
        unsigned ev = (li < m) ? edge_p[base + li] : 0u;
        int j = 0;
        for (; j + 16 <= m; j += 16)
            agg_batch_out<16>(ftb2, el, ev, j, li, erv, lam, ax, s);
        for (; j + 8 <= m; j += 8)
            agg_batch_out<8>(ftb2, el, ev, j, li, erv, lam, ax, s);
        if (j + 4 <= m) {
            agg_batch_out<4>(ftb2, el, ev, j, li, erv, lam, ax, s);
            j += 4;
        }
        for (; j < m; ++j)
            agg_batch_out<1>(ftb2, el, ev, j, li, erv, lam, ax, s);
    }

    float inv = (s > 0.f) ? 1.f / s : 0.f;
    float4 y;
    y.x = ax[0] * inv;
    y.y = ax[1] * inv;
    y.z = ax[2] * inv;
    y.w = ax[3] * inv;
    ((float4*)out)[(size_t)node * 16 + li] = y;
    ((float4*)out)[(size_t)(n + node) * 16 + li] = y;
}

// ---------------- launch ----------------

extern "C" void kernel_launch(void* const* d_in, const int* in_sizes, int n_in,
                              void* d_out, int out_size, void* d_ws, size_t ws_size,
                              hipStream_t stream) {
    const float* features = (const float*)d_in[0];
    const float* edge_weight = (const float*)d_in[1];
    const int* src = (const int*)d_in[2];
    const int* dst = (const int*)d_in[3];
    const float* W0 = (const float*)d_in[4];
    const float* al0 = (const float*)d_in[5];
    const float* ar0 = (const float*)d_in[6];
    const float* lam0 = (const float*)d_in[7];
    const float* W1 = (const float*)d_in[8];
    const float* al1 = (const float*)d_in[9];
    const float* ar1 = (const float*)d_in[10];
    const float* lam1 = (const float*)d_in[11];
    const float* W2 = (const float*)d_in[12];
    const float* al2 = (const float*)d_in[13];
    const float* ar2 = (const float*)d_in[14];
    const float* lam2 = (const float*)d_in[15];
    const float* g0 = (const float*)d_in[16];
    const float* b0 = (const float*)d_in[17];
    const float* g1 = (const float*)d_in[18];
    const float* b1 = (const float*)d_in[19];

    const int N = in_sizes[0] / 128;   // 50000 (< 65536: src fits 16 bits)
    const int E = in_sizes[1];

    char* w = (char*)d_ws;
    size_t o = 0;
    auto carve = [&](size_t bytes) {
        char* p = w + o;
        o += (bytes + 255) & ~(size_t)255;
        return p;
    };
    int* counts = (int*)carve((size_t)N * 64);       // 1 counter per 64B line
    int* dhist = (int*)carve(256);                   // 64-bin degree histogram
    int* dcount = (int*)carve(256);                  // scatter cursors
    int* rowptr = (int*)carve((size_t)(N + 1) * 4);
    int* bsum = (int*)carve(256 * 4);
    int* dbase = (int*)carve(256);
    int* rank = (int*)carve((size_t)E * 4);
    unsigned* edge_p = (unsigned*)carve((size_t)E * 4);
    int* perm = (int*)carve((size_t)N * 4);
    unsigned short* ftbA = (unsigned short*)carve((size_t)N * 128 * 2);
    unsigned short* ftbB = (unsigned short*)carve((size_t)N * 128 * 2);
    unsigned short* ftbC = (unsigned short*)carve((size_t)N * 64 * 2);
    unsigned short* h1 = (unsigned short*)carve((size_t)N * 128 * 2);
    float* elA = (float*)carve((size_t)N * 4 * 4);
    float* erA = (float*)carve((size_t)N * 4 * 4);
    float* elB = (float*)carve((size_t)N * 4 * 4);
    float* erB = (float*)carve((size_t)N * 4 * 4);
    float* elC = (float*)carve((size_t)N * 4);
    float* erC = (float*)carve((size_t)N * 4);
    unsigned short* Wt0 = (unsigned short*)carve(128 * 128 * 2);
    unsigned short* Wt1 = (unsigned short*)carve(128 * 128 * 2);
    unsigned short* Wt2 = (unsigned short*)carve(64 * 128 * 2);

    const int nscan = (N + 255) / 256;            // 196 (<=256 required by scan3)
    const int ngemm = (N + 63) / 64;
    const int nagg = (N + 15) / 16;
    const int RB = (E + 255) / 256;
    const int nz = N * 4 + 32;                    // uint4s: counts + dhist + dcount
    const int ZB = (nz + 1023) / 1024;

    // k0: zero counts+dhist+dcount, transpose W
    zero_wt_kernel<<<ZB + 160, 256, 0, stream>>>((uint4*)counts, nz, ZB,
                                                 W0, W1, W2, Wt0, Wt1, Wt2);
    // k1: degree histogram/rank + layer-0 GEMM (independent, fused)
    hist_gemm0<<<RB + ngemm, 256, 0, stream>>>(dst, counts, rank, E, RB,
                                               features, Wt0, al0, ar0,
                                               ftbA, elA, erA, N);
    // k2/k3: scan -> rowptr (+ degree-bin bases)
    scan1_kernel<<<nscan, 256, 0, stream>>>(counts, bsum, dhist, N);
    scan3_kernel<<<(N + 1 + 255) / 256, 256, 0, stream>>>(counts, bsum, rowptr,
                                                          dhist, dbase, N, E, nscan);
    // k4: edge placement + perm scatter
    place_kernel<<<RB + nscan, 256, 0, stream>>>(src, dst, edge_weight, rowptr, rank,
                                                 edge_p, dbase, dcount, perm, E, RB, N);
    // k5: agg0 (+h1) fused with gemm1
    fused_agg_gemm<true, 1><<<nagg, 256, 0, stream>>>(
        rowptr, edge_p, perm, (const uint4*)ftbA, elA, erA, lam0, g0, b0, features,
        (uint4*)h1, Wt1, al1, ar1, ftbB, elB, erB, N);
    // k6: agg1 fused with gemm2 (h2 never materialized)
    fused_agg_gemm<false, 2><<<nagg, 256, 0, stream>>>(
        rowptr, edge_p, perm, (const uint4*)ftbB, elB, erB, lam1, g1, b1, h1,
        nullptr, Wt2, al2, ar2, ftbC, elC, erC, N);
    // k7: final aggregate
    gat_agg_out<<<nagg, 256, 0, stream>>>(rowptr, edge_p, perm, (const uint2*)ftbC,
                                          elC, erC, lam2, (float*)d_out, N);
}

// Round 10
// 286.681 us; speedup vs baseline: 1.0449x; 1.0449x over previous
//
#include <hip/hip_runtime.h>

#define NEG_SLOPE 0.2f
#define LN_EPS 1e-5f

typedef __attribute__((ext_vector_type(8))) short bf16x8;
typedef __attribute__((ext_vector_type(4))) float f32x4;

__device__ inline unsigned short f2bf(float f) {
    unsigned u = __float_as_uint(f);
    unsigned r = u + 0x7FFFu + ((u >> 16) & 1u);   // round-to-nearest-even
    return (unsigned short)(r >> 16);
}

__device__ inline void unpack8(uint4 u, float* f) {
    f[0] = __uint_as_float(u.x << 16);
    f[1] = __uint_as_float(u.x & 0xFFFF0000u);
    f[2] = __uint_as_float(u.y << 16);
    f[3] = __uint_as_float(u.y & 0xFFFF0000u);
    f[4] = __uint_as_float(u.z << 16);
    f[5] = __uint_as_float(u.z & 0xFFFF0000u);
    f[6] = __uint_as_float(u.w << 16);
    f[7] = __uint_as_float(u.w & 0xFFFF0000u);
}

// ---------------- k0: zero counts+dhist+dcount + W transpose (fused) ------------

__global__ __launch_bounds__(256) void zero_wt_kernel(
    uint4* __restrict__ z, int nz, int ZB,
    const float* __restrict__ W0, const float* __restrict__ W1,
    const float* __restrict__ W2, unsigned short* __restrict__ Wt0,
    unsigned short* __restrict__ Wt1, unsigned short* __restrict__ Wt2) {
    int bid = blockIdx.x;
    if (bid < ZB) {
        int base = bid * 1024 + threadIdx.x;
        #pragma unroll
        for (int j = 0; j < 4; ++j) {
            int idx = base + j * 256;
            if (idx < nz) z[idx] = make_uint4(0, 0, 0, 0);
        }
    } else {
        int row = (bid - ZB) * 2 + (threadIdx.x >> 7);   // 0..319
        int k = threadIdx.x & 127;
        if (row < 128) {
            Wt0[row * 128 + k] = f2bf(W0[k * 128 + row]);
        } else if (row < 256) {
            int c = row - 128;
            Wt1[c * 128 + k] = f2bf(W1[k * 128 + c]);
        } else {
            int c = row - 256;
            Wt2[c * 128 + k] = f2bf(W2[k * 64 + c]);
        }
    }
}

// ---------------- k1: degree histogram (rank) + layer-0 GEMM, fused ----------------

__global__ __launch_bounds__(256) void hist_gemm0(
    const int* __restrict__ dst, int* __restrict__ counts, int* __restrict__ rank,
    int E, int RB, const float* __restrict__ Ap, const unsigned short* __restrict__ Wt,
    const float* __restrict__ al, const float* __restrict__ ar,
    unsigned short* __restrict__ ftb, float* __restrict__ el,
    float* __restrict__ er, int n) {
    constexpr int LDA = 136;  // bf16 elems per LDS row (128 + 8 pad)
    constexpr int NT = 8, H = 4, D = 32;
    __shared__ unsigned short As[64 * LDA];
    __shared__ unsigned short Ws[NT * 16 * LDA];
    int t = threadIdx.x;
    if (blockIdx.x < RB) {
        int i = blockIdx.x * 256 + t;
        if (i < E) rank[i] = atomicAdd(&counts[dst[i] * 16], 1);
        return;
    }
    int row0 = (blockIdx.x - RB) * 64;

    const float4* A4 = (const float4*)Ap;
    #pragma unroll
    for (int j = 0; j < 8; ++j) {
        int idx = t + j * 256;  // float4 index within 64x128 tile
        int r = idx >> 5;
        int c4 = idx & 31;
        int row = row0 + r;
        float4 v = (row < n) ? A4[(size_t)row * 32 + c4] : make_float4(0.f, 0.f, 0.f, 0.f);
        unsigned p0 = (unsigned)f2bf(v.x) | ((unsigned)f2bf(v.y) << 16);
        unsigned p1 = (unsigned)f2bf(v.z) | ((unsigned)f2bf(v.w) << 16);
        *(uint2*)&As[r * LDA + c4 * 4] = make_uint2(p0, p1);
    }
    const uint4* Wg = (const uint4*)Wt;
    #pragma unroll
    for (int j = 0; j < NT; ++j) {
        int idx = t + j * 256;
        int r = idx >> 4;
        int c8 = idx & 15;
        *(uint4*)&Ws[r * LDA + c8 * 8] = Wg[idx];
    }
    __syncthreads();

    int w = t >> 6, lane = t & 63;
    int m = lane & 15, q = lane >> 4;
    f32x4 acc[NT] = {};
    const unsigned short* ap = &As[(w * 16 + m) * LDA + q * 8];
    #pragma unroll
    for (int kk = 0; kk < 4; ++kk) {
        bf16x8 a = *(const bf16x8*)(ap + kk * 32);
        #pragma unroll
        for (int nt = 0; nt < NT; ++nt) {
            bf16x8 b = *(const bf16x8*)&Ws[(nt * 16 + m) * LDA + kk * 32 + q * 8];
            acc[nt] = __builtin_amdgcn_mfma_f32_16x16x32_bf16(a, b, acc[nt], 0, 0, 0);
        }
    }

    float alv[NT], arv[NT];
    #pragma unroll
    for (int nt = 0; nt < NT; ++nt) {
        alv[nt] = al[nt * 16 + m];
        arv[nt] = ar[nt * 16 + m];
    }

    int orow = row0 + w * 16 + q * 4;
    #pragma unroll
    for (int r = 0; r < 4; ++r) {
        int row = orow + r;
        float pl[H] = {}, pr[H] = {};
        #pragma unroll
        for (int nt = 0; nt < NT; ++nt) {
            int h = (nt * 16) / D;
            pl[h] = fmaf(acc[nt][r], alv[nt], pl[h]);
            pr[h] = fmaf(acc[nt][r], arv[nt], pr[h]);
        }
        #pragma unroll
        for (int off = 1; off < 16; off <<= 1) {
            #pragma unroll
            for (int h = 0; h < H; ++h) {
                pl[h] += __shfl_xor(pl[h], off, 64);
                pr[h] += __shfl_xor(pr[h], off, 64);
            }
        }
        if (row < n) {
            #pragma unroll
            for (int nt = 0; nt < NT; ++nt)
                ftb[(size_t)row * 128 + nt * 16 + m] = f2bf(acc[nt][r]);
            if (m < H) {
                float vl = pl[0], vr = pr[0];
                #pragma unroll
                for (int h = 1; h < H; ++h)
                    if (m == h) { vl = pl[h]; vr = pr[h]; }
                el[row * H + m] = vl;
                er[row * H + m] = vr;
            }
        }
    }
}

// ---------------- k2: scan1 — block sums + 64-bin degree histogram ----------------
// key = 63 - min(deg,63): descending-degree counting sort for the agg perm.

__global__ __launch_bounds__(256) void scan1_kernel(const int* __restrict__ counts,
                                                    int* __restrict__ bsum,
                                                    int* __restrict__ dhist, int n) {
    __shared__ int lds[256];
    __shared__ int hbin[64];
    int t = threadIdx.x;
    if (t < 64) hbin[t] = 0;
    int i = blockIdx.x * 256 + t;
    int c = (i < n) ? counts[i * 16] : 0;
    lds[t] = c;
    __syncthreads();
    if (i < n) atomicAdd(&hbin[63 - (c < 63 ? c : 63)], 1);
    for (int off = 128; off > 0; off >>= 1) {
        int v = (t < off) ? lds[t + off] : 0;
        __syncthreads();
        if (t < off) lds[t] += v;
        __syncthreads();
    }
    if (t == 0) bsum[blockIdx.x] = lds[0];
    if (t < 64) {
        int h = hbin[t];
        if (h) atomicAdd(&dhist[t], h);
    }
}

// ---------------- k3: fused scan2+scan3 -> rowptr; block0 scans dhist -> dbase ----

__global__ __launch_bounds__(256) void scan3_kernel(const int* __restrict__ counts,
                                                    const int* __restrict__ bsum,
                                                    int* __restrict__ rowptr,
                                                    const int* __restrict__ dhist,
                                                    int* __restrict__ dbase,
                                                    int n, int E, int nscan) {
    __shared__ int lds[256];
    int t = threadIdx.x;
    // pass A: inclusive scan of bsum
    lds[t] = (t < nscan) ? bsum[t] : 0;
    __syncthreads();
    for (int off = 1; off < 256; off <<= 1) {
        int v = (t >= off) ? lds[t - off] : 0;
        __syncthreads();
        lds[t] += v;
        __syncthreads();
    }
    int boff = (blockIdx.x > 0) ? lds[blockIdx.x - 1] : 0;
    __syncthreads();
    // pass B: scan this block's counts
    int i = blockIdx.x * 256 + t;
    int c = (i < n) ? counts[i * 16] : 0;
    lds[t] = c;
    __syncthreads();
    for (int off = 1; off < 256; off <<= 1) {
        int v = (t >= off) ? lds[t - off] : 0;
        __syncthreads();
        lds[t] += v;
        __syncthreads();
    }
    if (i < n) rowptr[i] = boff + lds[t] - c;  // exclusive prefix
    if (i == n) rowptr[n] = E;
    // bin scan (one wave)
    if (blockIdx.x == 0 && t < 64) {
        int v = dhist[t];
        int x = v;
        #pragma unroll
        for (int off = 1; off < 64; off <<= 1) {
            int u = __shfl_up(x, off, 64);
            if (t >= off) x += u;
        }
        dbase[t] = x - v;
    }
}

// ---------------- k4: placement + perm scatter ----------------

__global__ __launch_bounds__(256) void place_kernel(
    const int* __restrict__ src, const int* __restrict__ dst,
    const float* __restrict__ ew, const int* __restrict__ rowptr,
    const int* __restrict__ rank, unsigned* __restrict__ edge_p,
    const int* __restrict__ dbase, int* __restrict__ dcount,
    int* __restrict__ perm, int E, int EB, int N) {
    __shared__ int lbin[64];
    __shared__ int lbase[64];
    int bid = blockIdx.x;
    int t = threadIdx.x;
    if (bid < EB) {
        int i = bid * 256 + t;
        if (i < E) {
            int p = rowptr[dst[i]] + rank[i];
            edge_p[p] = ((unsigned)f2bf(ew[i]) << 16) | (unsigned)src[i];
        }
    } else {
        if (t < 64) lbin[t] = 0;
        __syncthreads();
        int nidx = (bid - EB) * 256 + t;
        bool valid = nidx < N;
        int key = 0, myoff = 0;
        if (valid) {
            int deg = rowptr[nidx + 1] - rowptr[nidx];
            key = 63 - (deg < 63 ? deg : 63);
            myoff = atomicAdd(&lbin[key], 1);
        }
        __syncthreads();
        if (t < 64) lbase[t] = lbin[t] ? atomicAdd(&dcount[t], lbin[t]) : 0;
        __syncthreads();
        if (valid) perm[dbase[key] + lbase[key] + myoff] = nidx;
    }
}

// ---------------- agg helpers ----------------

__device__ inline void accum8(float* ax, uint4 u, float p) {
    ax[0] = fmaf(p, __uint_as_float(u.x << 16), ax[0]);
    ax[1] = fmaf(p, __uint_as_float(u.x & 0xFFFF0000u), ax[1]);
    ax[2] = fmaf(p, __uint_as_float(u.y << 16), ax[2]);
    ax[3] = fmaf(p, __uint_as_float(u.y & 0xFFFF0000u), ax[3]);
    ax[4] = fmaf(p, __uint_as_float(u.z << 16), ax[4]);
    ax[5] = fmaf(p, __uint_as_float(u.z & 0xFFFF0000u), ax[5]);
    ax[6] = fmaf(p, __uint_as_float(u.w << 16), ax[6]);
    ax[7] = fmaf(p, __uint_as_float(u.w & 0xFFFF0000u), ax[7]);
}

__device__ inline void accum4(float* ax, uint2 u, float p) {
    ax[0] = fmaf(p, __uint_as_float(u.x << 16), ax[0]);
    ax[1] = fmaf(p, __uint_as_float(u.x & 0xFFFF0000u), ax[1]);
    ax[2] = fmaf(p, __uint_as_float(u.y << 16), ax[2]);
    ax[3] = fmaf(p, __uint_as_float(u.y & 0xFFFF0000u), ax[3]);
}

// K edges: issue K ftb gathers + K el loads before any consume (MLP depth K=8 max:
// R9 measured depth 16 = VGPR 76, occupancy −7pt, dur +11% — 8 is the HW sweet spot).
template <int K>
__device__ inline void agg_batch(const uint4* __restrict__ ftb4,
                                 const float* __restrict__ el, unsigned ev, int j,
                                 int li, int head, float erv, float lam, float* ax,
                                 float& s) {
    unsigned ee[K];
    uint4 uu[K];
    float ll[K];
    #pragma unroll
    for (int k = 0; k < K; ++k) ee[k] = __shfl(ev, j + k, 16);
    #pragma unroll
    for (int k = 0; k < K; ++k) {
        unsigned sn = ee[k] & 0xFFFFu;
        uu[k] = ftb4[(size_t)sn * 16 + li];
        ll[k] = el[sn * 4 + head];
    }
    #pragma unroll
    for (int k = 0; k < K; ++k) {
        float v = ll[k] + erv + lam * __uint_as_float(ee[k] & 0xFFFF0000u);
        v = fmaxf(v, NEG_SLOPE * v);
        float p = __expf(v);
        accum8(ax, uu[k], p);
        s += p;
    }
}

template <int K>
__device__ inline void agg_batch_out(const uint2* __restrict__ ftb2,
                                     const float* __restrict__ el, unsigned ev,
                                     int j, int li, float erv, float lam, float* ax,
                                     float& s) {
    unsigned ee[K];
    uint2 uu[K];
    float ll[K];
    #pragma unroll
    for (int k = 0; k < K; ++k) ee[k] = __shfl(ev, j + k, 16);
    #pragma unroll
    for (int k = 0; k < K; ++k) {
        unsigned sn = ee[k] & 0xFFFFu;
        uu[k] = ftb2[(size_t)sn * 16 + li];
        ll[k] = el[sn];
    }
    #pragma unroll
    for (int k = 0; k < K; ++k) {
        float v = ll[k] + erv + lam * __uint_as_float(ee[k] & 0xFFFF0000u);
        v = fmaxf(v, NEG_SLOPE * v);
        float p = __expf(v);
        accum4(ax, uu[k], p);
        s += p;
    }
}

// ---------------- k5/k6: fused agg+ELU+LN+residual THEN next-layer GEMM ----------
// Terminal config (R8): true-index tables, rank edge order (replay-stable
// numerics), descending-degree perm for processing order (kills the pre-GEMM
// barrier tail), K=8 gather pipeline, LDS-repacked uint4 epilogue.

template <bool PREV32, int VER>
__global__ __launch_bounds__(256) void fused_agg_gemm(
    const int* __restrict__ rowptr, const unsigned* __restrict__ edge_p,
    const int* __restrict__ perm, const uint4* __restrict__ ftb4,
    const float* __restrict__ el_in, const float* __restrict__ er_in,
    const float* __restrict__ lam_p, const float* __restrict__ g,
    const float* __restrict__ b, const void* __restrict__ prevp,
    uint4* __restrict__ houtb, const unsigned short* __restrict__ Wt,
    const float* __restrict__ al, const float* __restrict__ ar,
    unsigned short* __restrict__ ftb_out, float* __restrict__ el_out,
    float* __restrict__ er_out, int n) {
    constexpr int LDA = 136;
    __shared__ unsigned short As[16 * LDA];
    __shared__ float red[2][4][16];
    int t = threadIdx.x;
    int node0 = blockIdx.x * 16;
    int nl = t >> 4;
    int gid = node0 + nl;
    int li = t & 15;

    if (gid < n) {
        int node = perm[gid];
        int head = li >> 2;
        float lam = lam_p[0];
        float erv = er_in[node * 4 + head];
        int s0 = rowptr[node], s1 = rowptr[node + 1];
        float ax[8] = {};
        float s = 0.f;

        for (int base = s0; base < s1; base += 16) {
            int m = s1 - base;
            if (m > 16) m = 16;
            unsigned ev = (li < m) ? edge_p[base + li] : 0u;
            int j = 0;
            for (; j + 8 <= m; j += 8)
                agg_batch<8>(ftb4, el_in, ev, j, li, head, erv, lam, ax, s);
            if (j + 4 <= m) {
                agg_batch<4>(ftb4, el_in, ev, j, li, head, erv, lam, ax, s);
                j += 4;
            }
            for (; j < m; ++j)
                agg_batch<1>(ftb4, el_in, ev, j, li, head, erv, lam, ax, s);
        }

        float inv = (s > 0.f) ? 1.f / s : 0.f;
        float x[8];
        float sum = 0.f, sq = 0.f;
        #pragma unroll
        for (int d = 0; d < 8; ++d) {
            float v = ax[d] * inv;
            v = (v > 0.f) ? v : expm1f(v);
            x[d] = v;
            sum += v;
            sq += v * v;
        }
        #pragma unroll
        for (int off = 1; off < 16; off <<= 1) {
            sum += __shfl_xor(sum, off, 16);
            sq += __shfl_xor(sq, off, 16);
        }
        float mu = sum * (1.f / 128.f);
        float var = sq * (1.f / 128.f) - mu * mu;
        float rs = rsqrtf(var + LN_EPS);

        const float4* g4 = (const float4*)g;
        const float4* b4 = (const float4*)b;
        float pv[8];
        if constexpr (PREV32) {
            const float4* p4 = (const float4*)prevp;
            #pragma unroll
            for (int h = 0; h < 2; ++h) {
                float4 v = p4[(size_t)node * 32 + li * 2 + h];
                pv[h * 4 + 0] = v.x; pv[h * 4 + 1] = v.y;
                pv[h * 4 + 2] = v.z; pv[h * 4 + 3] = v.w;
            }
        } else {
            unpack8(((const uint4*)prevp)[(size_t)node * 16 + li], pv);
        }
        float y[8];
        #pragma unroll
        for (int h = 0; h < 2; ++h) {
            float4 gv = g4[li * 2 + h];
            float4 bv = b4[li * 2 + h];
            y[h * 4 + 0] = (x[h * 4 + 0] - mu) * rs * gv.x + bv.x + pv[h * 4 + 0];
            y[h * 4 + 1] = (x[h * 4 + 1] - mu) * rs * gv.y + bv.y + pv[h * 4 + 1];
            y[h * 4 + 2] = (x[h * 4 + 2] - mu) * rs * gv.z + bv.z + pv[h * 4 + 2];
            y[h * 4 + 3] = (x[h * 4 + 3] - mu) * rs * gv.w + bv.w + pv[h * 4 + 3];
        }
        uint4 o;
        o.x = (unsigned)f2bf(y[0]) | ((unsigned)f2bf(y[1]) << 16);
        o.y = (unsigned)f2bf(y[2]) | ((unsigned)f2bf(y[3]) << 16);
        o.z = (unsigned)f2bf(y[4]) | ((unsigned)f2bf(y[5]) << 16);
        o.w = (unsigned)f2bf(y[6]) | ((unsigned)f2bf(y[7]) << 16);
        if constexpr (VER == 1) houtb[(size_t)node * 16 + li] = o;
        *(uint4*)&As[nl * LDA + li * 8] = o;
    } else {
        *(uint4*)&As[nl * LDA + li * 8] = make_uint4(0, 0, 0, 0);
    }
    __syncthreads();

    // ---- GEMM phase on the 16 fresh rows (LDS row srow -> node perm[node0+srow]) --
    int w = t >> 6, lane = t & 63;
    int m = lane & 15, q = lane >> 4;
    if constexpr (VER == 1) {
        f32x4 acc[2] = {};
        #pragma unroll
        for (int kk = 0; kk < 4; ++kk) {
            bf16x8 a = *(const bf16x8*)&As[m * LDA + kk * 32 + q * 8];
            #pragma unroll
            for (int nt = 0; nt < 2; ++nt) {
                int col = w * 32 + nt * 16 + m;
                bf16x8 bb = *(const bf16x8*)&Wt[(size_t)col * 128 + kk * 32 + q * 8];
                acc[nt] = __builtin_amdgcn_mfma_f32_16x16x32_bf16(a, bb, acc[nt], 0, 0, 0);
            }
        }
        float alv0 = al[w * 32 + m], alv1 = al[w * 32 + 16 + m];
        float arv0 = ar[w * 32 + m], arv1 = ar[w * 32 + 16 + m];
        #pragma unroll
        for (int r = 0; r < 4; ++r) {
            int gr = node0 + q * 4 + r;
            float pl = acc[0][r] * alv0 + acc[1][r] * alv1;
            float pr = acc[0][r] * arv0 + acc[1][r] * arv1;
            #pragma unroll
            for (int off = 1; off < 16; off <<= 1) {
                pl += __shfl_xor(pl, off, 64);
                pr += __shfl_xor(pr, off, 64);
            }
            if (m == 0 && gr < n) {
                int trow = perm[gr];
                el_out[trow * 4 + w] = pl;
                er_out[trow * 4 + w] = pr;
            }
        }
        __syncthreads();   // all fragment reads done; safe to overwrite As
        #pragma unroll
        for (int r = 0; r < 4; ++r) {
            int srow = q * 4 + r;
            As[srow * LDA + w * 32 + m] = f2bf(acc[0][r]);
            As[srow * LDA + w * 32 + 16 + m] = f2bf(acc[1][r]);
        }
        __syncthreads();
        {
            int row = t >> 4, c8 = t & 15;
            int gr = node0 + row;
            if (gr < n)
                ((uint4*)ftb_out)[(size_t)perm[gr] * 16 + c8] =
                    *(const uint4*)&As[row * LDA + c8 * 8];
        }
    } else {
        f32x4 acc = {};
        #pragma unroll
        for (int kk = 0; kk < 4; ++kk) {
            bf16x8 a = *(const bf16x8*)&As[m * LDA + kk * 32 + q * 8];
            int col = w * 16 + m;
            bf16x8 bb = *(const bf16x8*)&Wt[(size_t)col * 128 + kk * 32 + q * 8];
            acc = __builtin_amdgcn_mfma_f32_16x16x32_bf16(a, bb, acc, 0, 0, 0);
        }
        float alv = al[w * 16 + m], arv = ar[w * 16 + m];
        #pragma unroll
        for (int r = 0; r < 4; ++r) {
            int srow = q * 4 + r;
            float pl = acc[r] * alv;
            float pr = acc[r] * arv;
            #pragma unroll
            for (int off = 1; off < 16; off <<= 1) {
                pl += __shfl_xor(pl, off, 64);
                pr += __shfl_xor(pr, off, 64);
            }
            if (m == 0) {
                red[0][w][srow] = pl;
                red[1][w][srow] = pr;
            }
        }
        __syncthreads();   // fragment reads + red writes done
        #pragma unroll
        for (int r = 0; r < 4; ++r) {
            int srow = q * 4 + r;
            As[srow * LDA + w * 16 + m] = f2bf(acc[r]);
        }
        __syncthreads();
        if (t < 128) {
            int row = t >> 3, c8 = t & 7;
            int gr = node0 + row;
            if (gr < n)
                ((uint4*)ftb_out)[(size_t)perm[gr] * 8 + c8] =
                    *(const uint4*)&As[row * LDA + c8 * 8];
        }
        if (t < 16) {
            int gr = node0 + t;
            if (gr < n) {
                int trow = perm[gr];
                el_out[trow] = red[0][0][t] + red[0][1][t] + red[0][2][t] + red[0][3][t];
                er_out[trow] = red[1][0][t] + red[1][1][t] + red[1][2][t] + red[1][3][t];
            }
        }
    }
}

// ---------------- k7: final aggregate (H=1, OUT=64) ----------------

__global__ __launch_bounds__(256) void gat_agg_out(
    const int* __restrict__ rowptr, const unsigned* __restrict__ edge_p,
    const int* __restrict__ perm, const uint2* __restrict__ ftb2,
    const float* __restrict__ el, const float* __restrict__ er,
    const float* __restrict__ lam_p, float* __restrict__ out, int n) {
    int gid = blockIdx.x * 16 + (threadIdx.x >> 4);
    if (gid >= n) return;
    int node = perm[gid];
    int li = threadIdx.x & 15;
    float lam = lam_p[0];
    float erv = er[node];
    int s0 = rowptr[node], s1 = rowptr[node + 1];
    float ax[4] = {};
    float s = 0.f;

    for (int base = s0; base < s1; base += 16) {
        int m = s1 - base;
        if (m > 16) m = 16;
        unsigned ev = (li < m) ? edge_p[base + li] : 0u;
        int j = 0;
        for (; j + 8 <= m; j += 8)
            agg_batch_out<8>(ftb2, el, ev, j, li, erv, lam, ax, s);
        if (j + 4 <= m) {
            agg_batch_out<4>(ftb2, el, ev, j, li, erv, lam, ax, s);
            j += 4;
        }
        for (; j < m; ++j)
            agg_batch_out<1>(ftb2, el, ev, j, li, erv, lam, ax, s);
    }

    float inv = (s > 0.f) ? 1.f / s : 0.f;
    float4 y;
    y.x = ax[0] * inv;
    y.y = ax[1] * inv;
    y.z = ax[2] * inv;
    y.w = ax[3] * inv;
    ((float4*)out)[(size_t)node * 16 + li] = y;
    ((float4*)out)[(size_t)(n + node) * 16 + li] = y;
}

// ---------------- launch ----------------

extern "C" void kernel_launch(void* const* d_in, const int* in_sizes, int n_in,
                              void* d_out, int out_size, void* d_ws, size_t ws_size,
                              hipStream_t stream) {
    const float* features = (const float*)d_in[0];
    const float* edge_weight = (const float*)d_in[1];
    const int* src = (const int*)d_in[2];
    const int* dst = (const int*)d_in[3];
    const float* W0 = (const float*)d_in[4];
    const float* al0 = (const float*)d_in[5];
    const float* ar0 = (const float*)d_in[6];
    const float* lam0 = (const float*)d_in[7];
    const float* W1 = (const float*)d_in[8];
    const float* al1 = (const float*)d_in[9];
    const float* ar1 = (const float*)d_in[10];
    const float* lam1 = (const float*)d_in[11];
    const float* W2 = (const float*)d_in[12];
    const float* al2 = (const float*)d_in[13];
    const float* ar2 = (const float*)d_in[14];
    const float* lam2 = (const float*)d_in[15];
    const float* g0 = (const float*)d_in[16];
    const float* b0 = (const float*)d_in[17];
    const float* g1 = (const float*)d_in[18];
    const float* b1 = (const float*)d_in[19];

    const int N = in_sizes[0] / 128;   // 50000 (< 65536: src fits 16 bits)
    const int E = in_sizes[1];

    char* w = (char*)d_ws;
    size_t o = 0;
    auto carve = [&](size_t bytes) {
        char* p = w + o;
        o += (bytes + 255) & ~(size_t)255;
        return p;
    };
    int* counts = (int*)carve((size_t)N * 64);       // 1 counter per 64B line
    int* dhist = (int*)carve(256);                   // 64-bin degree histogram
    int* dcount = (int*)carve(256);                  // scatter cursors
    int* rowptr = (int*)carve((size_t)(N + 1) * 4);
    int* bsum = (int*)carve(256 * 4);
    int* dbase = (int*)carve(256);
    int* rank = (int*)carve((size_t)E * 4);
    unsigned* edge_p = (unsigned*)carve((size_t)E * 4);
    int* perm = (int*)carve((size_t)N * 4);
    unsigned short* ftbA = (unsigned short*)carve((size_t)N * 128 * 2);
    unsigned short* ftbB = (unsigned short*)carve((size_t)N * 128 * 2);
    unsigned short* ftbC = (unsigned short*)carve((size_t)N * 64 * 2);
    unsigned short* h1 = (unsigned short*)carve((size_t)N * 128 * 2);
    float* elA = (float*)carve((size_t)N * 4 * 4);
    float* erA = (float*)carve((size_t)N * 4 * 4);
    float* elB = (float*)carve((size_t)N * 4 * 4);
    float* erB = (float*)carve((size_t)N * 4 * 4);
    float* elC = (float*)carve((size_t)N * 4);
    float* erC = (float*)carve((size_t)N * 4);
    unsigned short* Wt0 = (unsigned short*)carve(128 * 128 * 2);
    unsigned short* Wt1 = (unsigned short*)carve(128 * 128 * 2);
    unsigned short* Wt2 = (unsigned short*)carve(64 * 128 * 2);

    const int nscan = (N + 255) / 256;            // 196 (<=256 required by scan3)
    const int ngemm = (N + 63) / 64;
    const int nagg = (N + 15) / 16;
    const int RB = (E + 255) / 256;
    const int nz = N * 4 + 32;                    // uint4s: counts + dhist + dcount
    const int ZB = (nz + 1023) / 1024;

    // k0: zero counts+dhist+dcount, transpose W
    zero_wt_kernel<<<ZB + 160, 256, 0, stream>>>((uint4*)counts, nz, ZB,
                                                 W0, W1, W2, Wt0, Wt1, Wt2);
    // k1: degree histogram/rank + layer-0 GEMM (independent, fused)
    hist_gemm0<<<RB + ngemm, 256, 0, stream>>>(dst, counts, rank, E, RB,
                                               features, Wt0, al0, ar0,
                                               ftbA, elA, erA, N);
    // k2/k3: scan -> rowptr (+ degree-bin bases)
    scan1_kernel<<<nscan, 256, 0, stream>>>(counts, bsum, dhist, N);
    scan3_kernel<<<(N + 1 + 255) / 256, 256, 0, stream>>>(counts, bsum, rowptr,
                                                          dhist, dbase, N, E, nscan);
    // k4: edge placement + perm scatter
    place_kernel<<<RB + nscan, 256, 0, stream>>>(src, dst, edge_weight, rowptr, rank,
                                                 edge_p, dbase, dcount, perm, E, RB, N);
    // k5: agg0 (+h1) fused with gemm1
    fused_agg_gemm<true, 1><<<nagg, 256, 0, stream>>>(
        rowptr, edge_p, perm, (const uint4*)ftbA, elA, erA, lam0, g0, b0, features,
        (uint4*)h1, Wt1, al1, ar1, ftbB, elB, erB, N);
    // k6: agg1 fused with gemm2 (h2 never materialized)
    fused_agg_gemm<false, 2><<<nagg, 256, 0, stream>>>(
        rowptr, edge_p, perm, (const uint4*)ftbB, elB, erB, lam1, g1, b1, h1,
        nullptr, Wt2, al2, ar2, ftbC, elC, erC, N);
    // k7: final aggregate
    gat_agg_out<<<nagg, 256, 0, stream>>>(rowptr, edge_p, perm, (const uint2*)ftbC,
                                          elC, erC, lam2, (float*)d_out, N);
}